// Round 7
// baseline (95.208 us; speedup 1.0000x reference)
//
#include <hip/hip_runtime.h>
#include <hip/hip_bf16.h>

#define S_LEN 2048
#define HIDDEN 1024

typedef __attribute__((ext_vector_type(4))) float f32x4;
typedef __attribute__((ext_vector_type(8))) _Float16 f16x8;
typedef __attribute__((ext_vector_type(2))) _Float16 f16x2;
typedef __attribute__((ext_vector_type(2))) __fp16 fp16x2;
typedef unsigned short u16;
typedef unsigned int u32;

typedef const __attribute__((address_space(1))) unsigned int as1_u32;
typedef __attribute__((address_space(3))) unsigned int as3_u32;

__device__ __forceinline__ u16 f2h(float f) {
  union { _Float16 h; u16 u; } c; c.h = (_Float16)f; return c.u;
}
__device__ __forceinline__ f16x2 u2h2(u32 u) {
  union { u32 x; f16x2 h; } c; c.x = u; return c.h;
}
__device__ __forceinline__ float fdot2(u32 a, u32 b, float c) {
#if __has_builtin(__builtin_amdgcn_fdot2)
  return __builtin_amdgcn_fdot2(u2h2(a), u2h2(b), c, false);
#else
  f16x2 ha = u2h2(a), hb = u2h2(b);
  return fmaf((float)ha.x, (float)hb.x, fmaf((float)ha.y, (float)hb.y, c));
#endif
}
__device__ __forceinline__ u32 pkrtz(float a, float b) {
#if __has_builtin(__builtin_amdgcn_cvt_pkrtz)
  union { fp16x2 h; u32 u; } c;
  c.h = __builtin_amdgcn_cvt_pkrtz(a, b);
  return c.u;
#else
  union { f16x2 h; u32 u; } c;
  c.h.x = (_Float16)a; c.h.y = (_Float16)b;
  return c.u;
#endif
}

// ---------------- fused f32 -> f16 convert (all 5 arrays) ----------------
__global__ __launch_bounds__(256) void cvt_all(
    const float* __restrict__ h, const float* __restrict__ qw,
    const float* __restrict__ kw, const float* __restrict__ vw,
    const float* __restrict__ ow, u16* __restrict__ hb, u16* __restrict__ qwb,
    u16* __restrict__ kwb, u16* __restrict__ vwb, u16* __restrict__ owb) {
  const int b = blockIdx.x;
  const float* src; u16* dst; int base;
  if (b < 2048)      { src = h;  dst = hb;  base = b; }
  else if (b < 3072) { src = qw; dst = qwb; base = b - 2048; }
  else if (b < 3584) { src = kw; dst = kwb; base = b - 3072; }
  else if (b < 4096) { src = vw; dst = vwb; base = b - 3584; }
  else               { src = ow; dst = owb; base = b - 4096; }
  const int i = base * 256 + threadIdx.x;
  const float4 v = ((const float4*)src)[i];
  ushort4 r;
  r.x = f2h(v.x); r.y = f2h(v.y); r.z = f2h(v.z); r.w = f2h(v.w);
  ((ushort4*)dst)[i] = r;
}

// ---------------- f16 GEMM core: C = A(MxK) * W(NxK)^T ----------------
template <int BM, bool OUT_F16>
__device__ __forceinline__ void gemm_core(
    u16* __restrict__ As, u16* __restrict__ Bs,
    const u16* __restrict__ A, const u16* __restrict__ W, void* __restrict__ Cv,
    int Kd, int ldc, int mtile, int ntile) {
  constexpr int MF = BM / 32;
  const int tid = threadIdx.x;
  const int lane = tid & 63;
  const int wave = tid >> 6;
  const int wr = wave >> 1, wc = wave & 1;
  f32x4 acc[MF][4] = {};
  const int m0 = mtile * BM, n0 = ntile * 128;

  for (int kt = 0; kt < Kd; kt += 32) {
#pragma unroll
    for (int i = 0; i < BM / 64; ++i) {
      const int e = (i * 256 + tid) * 8;
      const int r = e >> 5, c = e & 31;
      __builtin_amdgcn_global_load_lds(
          (as1_u32*)(A + (size_t)(m0 + r) * Kd + kt + c), (as3_u32*)(As + e), 16, 0, 0);
    }
#pragma unroll
    for (int i = 0; i < 2; ++i) {
      const int e = (i * 256 + tid) * 8;
      const int r = e >> 5, c = e & 31;
      __builtin_amdgcn_global_load_lds(
          (as1_u32*)(W + (size_t)(n0 + r) * Kd + kt + c), (as3_u32*)(Bs + e), 16, 0, 0);
    }
    __syncthreads();
    f16x8 af[MF], bfr[4];
#pragma unroll
    for (int mi = 0; mi < MF; ++mi)
      af[mi] = *(const f16x8*)(As + (wr * (BM / 2) + mi * 16 + (lane & 15)) * 32 + (lane >> 4) * 8);
#pragma unroll
    for (int ni = 0; ni < 4; ++ni)
      bfr[ni] = *(const f16x8*)(Bs + (wc * 64 + ni * 16 + (lane & 15)) * 32 + (lane >> 4) * 8);
#pragma unroll
    for (int mi = 0; mi < MF; ++mi)
#pragma unroll
      for (int ni = 0; ni < 4; ++ni)
        acc[mi][ni] = __builtin_amdgcn_mfma_f32_16x16x32_f16(af[mi], bfr[ni], acc[mi][ni], 0, 0, 0);
    __syncthreads();
  }

#pragma unroll
  for (int mi = 0; mi < MF; ++mi) {
#pragma unroll
    for (int ni = 0; ni < 4; ++ni) {
      const int row0 = m0 + wr * (BM / 2) + mi * 16 + (lane >> 4) * 4;
      const int col = n0 + wc * 64 + ni * 16 + (lane & 15);
#pragma unroll
      for (int r = 0; r < 4; ++r) {
        if (OUT_F16)
          ((u16*)Cv)[(size_t)(row0 + r) * ldc + col] = f2h(acc[mi][ni][r]);
        else
          ((float*)Cv)[(size_t)(row0 + r) * ldc + col] = acc[mi][ni][r];
      }
    }
  }
}

__global__ __launch_bounds__(256, 2) void qkv_gemm(
    const u16* __restrict__ hb, const u16* __restrict__ qwb,
    const u16* __restrict__ kwb, const u16* __restrict__ vwb,
    u16* __restrict__ Qb, u16* __restrict__ Kb, u16* __restrict__ Vb) {
  __shared__ u16 As[128 * 32];
  __shared__ u16 Bs[128 * 32];
  const int nt = blockIdx.x, mt = blockIdx.y;
  if (nt < 8)       gemm_core<128, true>(As, Bs, hb, qwb, Qb, HIDDEN, 1024, mt, nt);
  else if (nt < 12) gemm_core<128, true>(As, Bs, hb, kwb, Kb, HIDDEN, 512, mt, nt - 8);
  else              gemm_core<128, true>(As, Bs, hb, vwb, Vb, HIDDEN, 512, mt, nt - 12);
}

__global__ __launch_bounds__(256, 2) void o_gemm(
    const u16* __restrict__ attnb, const u16* __restrict__ owb,
    float* __restrict__ out) {
  __shared__ u16 As[64 * 32];
  __shared__ u16 Bs[128 * 32];
  gemm_core<64, false>(As, Bs, attnb, owb, out, HIDDEN, 1024, blockIdx.y, blockIdx.x);
}

// ---------------- gathered attention ----------------
// 4 waves / block = 4 consecutive queries (same h). Window K and V rows
// (72) staged shared in LDS via global_load_lds (pre-swizzled source);
// random K rows gathered directly into REGISTERS (8 uint4/lane). Low LDS
// (21KB) + VGPR cap -> 5 blocks/CU for latency hiding.
#define WIN_ROWS 72
#define WIN_ELEMS (WIN_ROWS * 64)
__global__ __launch_bounds__(256, 5) void attn_kernel(
    const u16* __restrict__ Qb, const u16* __restrict__ Kb,
    const u16* __restrict__ Vb, const int* __restrict__ neigh,
    const float* __restrict__ ebias, u16* __restrict__ attnb) {
  __shared__ u16 kwin[WIN_ELEMS];     // 9KB
  __shared__ u16 vwin[WIN_ELEMS];     // 9KB
  __shared__ u32 park[4][192];        // 3KB: 128 u32 packed p + 64 idx

  const int tid = threadIdx.x;
  const int lane = tid & 63;
  const int wv = tid >> 6;
  const int h = blockIdx.y;
  const int s0 = blockIdx.x * 4;
  const int s = s0 + wv;

  const u16* Kp = Kb + h * 64;
  const u16* Vp = Vb + h * 64;

  // random-half neighbor (window half structural: idx = s - j)
  const int iB = neigh[((size_t)h * S_LEN + s) * 128 + 64 + lane];
  const bool okB = (iB >= 0) && (iB <= s);
  const int gB = min(max(iB, 0), S_LEN - 1);
  const bool okA = lane <= s;

  // ---- random K row -> registers (8 x uint4, independent loads) ----
  const u16* krp = Kp + (size_t)gB * 512;
  uint4 krreg[8];
#pragma unroll
  for (int t = 0; t < 8; ++t) krreg[t] = *(const uint4*)(krp + t * 8);

  // ---- window K/V staging (shared): 9 groups of 8 rows each ----
  const int chunk = (lane & 7) ^ (lane >> 3);   // pre-swizzled global source
#pragma unroll
  for (int gg = 0; gg < 2; ++gg) {
    const int g = wv + gg * 4;
    const int r_lds = g * 8 + (lane >> 3);
    const int row = min(max(s0 - 63 + r_lds, 0), S_LEN - 1);
    __builtin_amdgcn_global_load_lds(
        (as1_u32*)(Kp + (size_t)row * 512 + chunk * 8),
        (as3_u32*)(kwin + g * 512 + lane * 8), 16, 0, 0);
    __builtin_amdgcn_global_load_lds(
        (as1_u32*)(Vp + (size_t)row * 512 + chunk * 8),
        (as3_u32*)(vwin + g * 512 + lane * 8), 16, 0, 0);
  }
  if (wv == 0) {
    const int g = 8;
    const int r_lds = g * 8 + (lane >> 3);
    const int row = min(max(s0 - 63 + r_lds, 0), S_LEN - 1);
    __builtin_amdgcn_global_load_lds(
        (as1_u32*)(Kp + (size_t)row * 512 + chunk * 8),
        (as3_u32*)(kwin + g * 512 + lane * 8), 16, 0, 0);
    __builtin_amdgcn_global_load_lds(
        (as1_u32*)(Vp + (size_t)row * 512 + chunk * 8),
        (as3_u32*)(vwin + g * 512 + lane * 8), 16, 0, 0);
  }

  __syncthreads();   // drains vmcnt (incl. krreg) + all staging visible

  // ---- scores: lane = neighbor j ----
  const u16* qp = Qb + (size_t)s * 1024 + h * 128;
  const int rW = wv + 63 - lane;           // window row in [0, 66]
  const u16* kwrow = kwin + rW * 64;
  const int rw7 = rW & 7;
  float sA0 = 0.f, sA1 = 0.f, sB0 = 0.f, sB1 = 0.f;
#pragma unroll
  for (int t = 0; t < 8; ++t) {
    const uint4 kw = *(const uint4*)(kwrow + ((t ^ rw7) << 3));
    const uint4 kr = krreg[t];
    const uint4 qa = *(const uint4*)(qp + t * 8);
    const uint4 qb = *(const uint4*)(qp + 64 + t * 8);
    sA0 = fdot2(kw.x, qa.x, sA0); sA0 = fdot2(kw.y, qa.y, sA0);
    sA0 = fdot2(kw.z, qa.z, sA0); sA0 = fdot2(kw.w, qa.w, sA0);
    sA1 = fdot2(kw.x, qb.x, sA1); sA1 = fdot2(kw.y, qb.y, sA1);
    sA1 = fdot2(kw.z, qb.z, sA1); sA1 = fdot2(kw.w, qb.w, sA1);
    sB0 = fdot2(kr.x, qa.x, sB0); sB0 = fdot2(kr.y, qa.y, sB0);
    sB0 = fdot2(kr.z, qa.z, sB0); sB0 = fdot2(kr.w, qa.w, sB0);
    sB1 = fdot2(kr.x, qb.x, sB1); sB1 = fdot2(kr.y, qb.y, sB1);
    sB1 = fdot2(kr.z, qb.z, sB1); sB1 = fdot2(kr.w, qb.w, sB1);
  }

  const float NEG = -1e30f;
  const float SC = 0.125f;            // 64^-0.5
  const float ebW = ebias[1];
  const float ebR = ebias[3];
  sA0 = okA ? fmaf(sA0, SC, ebW) : NEG;
  sA1 = okA ? fmaf(sA1, SC, ebW) : NEG;
  sB0 = okB ? fmaf(sB0, SC, ebR) : NEG;
  sB1 = okB ? fmaf(sB1, SC, ebR) : NEG;

  // ---- softmax over 128 scores (2 per lane per g) ----
  float m0 = fmaxf(sA0, sB0), m1 = fmaxf(sA1, sB1);
#pragma unroll
  for (int off = 32; off; off >>= 1) {
    m0 = fmaxf(m0, __shfl_xor(m0, off));
    m1 = fmaxf(m1, __shfl_xor(m1, off));
  }
  float eA0 = __expf(sA0 - m0), eB0 = __expf(sB0 - m0);
  float eA1 = __expf(sA1 - m1), eB1 = __expf(sB1 - m1);
  float d0 = eA0 + eB0, d1 = eA1 + eB1;
#pragma unroll
  for (int off = 32; off; off >>= 1) {
    d0 += __shfl_xor(d0, off);
    d1 += __shfl_xor(d1, off);
  }
  const float rc0 = 1.0f / d0, rc1 = 1.0f / d1;

  // ---- park packed f16 p-pairs + idx ----
  u32* pb = park[wv];
  int* ib = (int*)(park[wv] + 128);
  const float pA0 = eA0 * rc0, pA1 = eA1 * rc1;
  const float pB0 = eB0 * rc0, pB1 = eB1 * rc1;
  const float hA0 = __shfl_xor(pA0, 1), hA1 = __shfl_xor(pA1, 1);
  const float hB0 = __shfl_xor(pB0, 1), hB1 = __shfl_xor(pB1, 1);
  ib[lane] = gB;
  if (!(lane & 1)) {
    uint4 pk;
    pk.x = pkrtz(pA0, hA0);
    pk.y = pkrtz(pA1, hA1);
    pk.z = pkrtz(pB0, hB0);
    pk.w = pkrtz(pB1, hB1);
    *(uint4*)(pb + (lane >> 1) * 4) = pk;
  }
  asm volatile("s_waitcnt lgkmcnt(0)" ::: "memory");

  // ---- PV: lane = d; window V from LDS, random V coalesced global ----
  float a0 = 0.f, a1 = 0.f;
  const int ln7 = lane & 7, lnc = lane >> 3;
#pragma unroll 4
  for (int m = 0; m < 32; ++m) {
    const uint4 pp = *(const uint4*)(pb + m * 4);
    const int2 rB = *(const int2*)(ib + m * 2);
    const int rl0 = wv + 63 - 2 * m;          // window row for j=2m
    const int rl1 = rl0 - 1;                  // j=2m+1 (may be -1 at m=31? no: >= wv)
    // swizzled LDS u16 read: row r, dim lane
    const int a0i = (rl0 >> 3) * 512 + ((rl0 & 7) * 8 + (lnc ^ (rl0 & 7))) * 8 + ln7;
    const int a1i = (rl1 >> 3) * 512 + ((rl1 & 7) * 8 + (lnc ^ (rl1 & 7))) * 8 + ln7;
    const u32 w0 = vwin[a0i];
    const u32 w1 = vwin[a1i];
    const u32 b0 = Vp[(size_t)rB.x * 512 + lane];
    const u32 b1 = Vp[(size_t)rB.y * 512 + lane];
    const u32 wpair = (w1 << 16) | w0;
    const u32 bpair = (b1 << 16) | b0;
    a0 = fdot2(wpair, pp.x, a0);
    a1 = fdot2(wpair, pp.y, a1);
    a0 = fdot2(bpair, pp.z, a0);
    a1 = fdot2(bpair, pp.w, a1);
  }

  u16* op = attnb + (size_t)s * 1024 + h * 128;
  op[lane] = f2h(a0);
  op[64 + lane] = f2h(a1);
}

extern "C" void kernel_launch(void* const* d_in, const int* in_sizes, int n_in,
                              void* d_out, int out_size, void* d_ws, size_t ws_size,
                              hipStream_t stream) {
  const float* hidden = (const float*)d_in[0];
  const float* q_w = (const float*)d_in[1];
  const float* k_w = (const float*)d_in[2];
  const float* v_w = (const float*)d_in[3];
  const float* o_w = (const float*)d_in[4];
  const float* ebias = (const float*)d_in[5];
  const int* neigh = (const int*)d_in[6];
  float* out = (float*)d_out;

  char* ws = (char*)d_ws;
  u16* hb    = (u16*)(ws + (0ull << 20));    // 4MB
  u16* qwb   = (u16*)(ws + (4ull << 20));    // 2MB
  u16* kwb   = (u16*)(ws + (6ull << 20));    // 1MB
  u16* vwb   = (u16*)(ws + (7ull << 20));    // 1MB
  u16* owb   = (u16*)(ws + (8ull << 20));    // 2MB
  u16* Qb    = (u16*)(ws + (10ull << 20));   // 4MB
  u16* Kb    = (u16*)(ws + (14ull << 20));   // 2MB
  u16* Vb    = (u16*)(ws + (16ull << 20));   // 2MB
  u16* attnb = (u16*)(ws + (18ull << 20));   // 4MB

  cvt_all<<<5120, 256, 0, stream>>>(hidden, q_w, k_w, v_w, o_w,
                                    hb, qwb, kwb, vwb, owb);
  qkv_gemm<<<dim3(16, 16), 256, 0, stream>>>(hb, qwb, kwb, vwb, Qb, Kb, Vb);
  attn_kernel<<<dim3(512, 8), 256, 0, stream>>>(Qb, Kb, Vb, neigh, ebias, attnb);
  o_gemm<<<dim3(8, 32), 256, 0, stream>>>(attnb, owb, out);
}